// Round 5
// baseline (425.681 us; speedup 1.0000x reference)
//
#include <hip/hip_runtime.h>
#include <stdint.h>

// Problem constants: B=4, C=128, H=W=128, N=9, OC=256, stride=1
#define CIN   128
#define HDIM  128
#define WDIM  128
#define HWSZ  16384
#define NP    9
#define OCH   256
#define KDIM  1152

typedef __bf16 bf16_t;
typedef __bf16 bf16x8 __attribute__((ext_vector_type(8)));
typedef float  f32x4  __attribute__((ext_vector_type(4)));
typedef __fp16 f16x2 __attribute__((ext_vector_type(2)));   // matches cvt_pkrtz return
struct __attribute__((packed, aligned(4))) F2 { float x, y; };

// XCD-locality swizzle (grid=512): XCD k gets a contiguous band of 64
// logical (b,ii) blocks so its 4MB L2 holds the x rows it needs.
__device__ __forceinline__ int swz(int hw) { return (hw & 7) * 64 + (hw >> 3); }

// ---------------------------------------------------------------------------
// B_T[o][k] bf16, k = n*128 + c  (= w_conv[o][c][n])
// ---------------------------------------------------------------------------
__global__ void k_bt(const float* __restrict__ wc, bf16_t* __restrict__ bt) {
  int c = threadIdx.x, n = blockIdx.x, o = blockIdx.y;
  bt[o * KDIM + n * 128 + c] = (bf16_t)wc[(o * CIN + c) * NP + n];
}

// ---------------------------------------------------------------------------
// Offset conv (3x3 pad 1, 128->18) in PURE FP32 + bilinear meta.
// fp32 REQUIRED: bilinear is discontinuous at borders (clamped corner weights
// sum to 2); ~1e-3 offset error flips samples (round-2 failure).
// 512 threads = 128 j x 4 c-quarters (4 waves/SIMD for latency hiding;
// round-3's 256-thr version had 2 waves/SIMD and sat at ~150us).
// ---------------------------------------------------------------------------
__global__ __launch_bounds__(512) void k_conv_meta(
    const float* __restrict__ x, const float* __restrict__ wp,
    const float* __restrict__ bp, int* __restrict__ midx,
    float4* __restrict__ mw)
{
  __shared__ float red[4 * 128 * 19];   // [cq][j] stride 19: conflict-free

  int blk = swz(blockIdx.x);
  int bb = blk >> 7, ii = blk & 127;
  int tid = threadIdx.x;
  int j = tid & 127;
  int cq = tid >> 7;          // wave-uniform (wave w -> cq = w>>1)

  float acc[18];
#pragma unroll
  for (int o = 0; o < 18; ++o) acc[o] = 0.f;

  for (int c = cq * 32; c < cq * 32 + 32; ++c) {
    int cu = __builtin_amdgcn_readfirstlane(c);
    const float* xc = x + ((size_t)bb * CIN + cu) * HWSZ;
    float xv[9];
#pragma unroll
    for (int dy = 0; dy < 3; ++dy) {
      int r = ii + dy - 1;
      bool rok = ((unsigned)r < 128u);
#pragma unroll
      for (int dx = 0; dx < 3; ++dx) {
        int cc = j + dx - 1;
        bool ok = rok && ((unsigned)cc < 128u);
        xv[dy * 3 + dx] = ok ? xc[r * 128 + cc] : 0.f;
      }
    }
    const float* wr = wp + cu * 9;   // uniform -> s_load
#pragma unroll
    for (int o = 0; o < 18; ++o) {
#pragma unroll
      for (int t = 0; t < 9; ++t)
        acc[o] += xv[t] * wr[o * 1152 + t];
    }
  }

  {
    float* rr = &red[(cq * 128 + j) * 19];
#pragma unroll
    for (int o = 0; o < 18; ++o) rr[o] = acc[o];
  }
  __syncthreads();

  if (tid < 128) {
#pragma unroll
    for (int o = 0; o < 18; ++o)
      acc[o] = red[(0 * 128 + j) * 19 + o] + red[(1 * 128 + j) * 19 + o] +
               red[(2 * 128 + j) * 19 + o] + red[(3 * 128 + j) * 19 + o];

#pragma unroll
    for (int n = 0; n < NP; ++n) {
      float offx = acc[n] + bp[n];
      float offy = acc[9 + n] + bp[9 + n];
      float px = (float)ii + (float)(n / 3) + offx;
      float py = (float)j  + (float)(n % 3) + offy;
      float f0 = floorf(px), f1 = f0 + 1.f;
      float h0 = floorf(py), h1 = h0 + 1.f;
      int r0 = (int)fminf(fmaxf(f0, 0.f), 127.f);
      int r1 = (int)fminf(fmaxf(f1, 0.f), 127.f);
      int c0 = (int)fminf(fmaxf(h0, 0.f), 127.f);
      int c1 = (int)fminf(fmaxf(h1, 0.f), 127.f);
      float pxc = fminf(fmaxf(px, 0.f), 127.f);
      float pyc = fminf(fmaxf(py, 0.f), 127.f);
      float glt = (1.f + ((float)r0 - pxc)) * (1.f + ((float)c0 - pyc));
      float grb = (1.f - ((float)r1 - pxc)) * (1.f - ((float)c1 - pyc));
      float glb = (1.f + ((float)r0 - pxc)) * (1.f - ((float)c1 - pyc));
      float grt = (1.f - ((float)r1 - pxc)) * (1.f + ((float)c0 - pyc));
      int base = ((bb * 128 + ii) * NP + n) * 128 + j;
      midx[base] = r0 | (r1 << 8) | (c0 << 16) | (c1 << 24);
      mw[base] = make_float4(glt, grb, glb, grt);
    }
  }
}

// ---------------------------------------------------------------------------
// Fused gather + GEMM, LDS-window edition. One block per (b,ii).
// Chunk order: tier t=i/12 (n/3), cg=(i%12)/3, nn=i%3; n=t*3+nn.
// Window: 6 rows x 32ch x 128col fp16 (49152B) staged coalesced per (t,cg);
// gather = 2 LDS dword-pair reads per (ch,row) instead of scattered VMEM
// (round-3 was TA-bound: 9216 scattered wave-loads/CU at ~45cyc = 174us).
// LDS: W @0 (49152) | A @49152 (10240, stride 40elem) | B @59392 (18432,
// stride 36elem = conflict-free frag reads). Total 77824 -> 2 blocks/CU.
// ---------------------------------------------------------------------------
__global__ __launch_bounds__(512, 4) void k_gemm(
    const float* __restrict__ x, const bf16_t* __restrict__ bt,
    const int* __restrict__ midx, const float4* __restrict__ mw,
    float* __restrict__ out)
{
  __shared__ __align__(16) char smem[77824];
  bf16_t* Ald = (bf16_t*)(smem + 49152);
  bf16_t* Bld = (bf16_t*)(smem + 59392);

  int blk = swz(blockIdx.x);
  int bb = blk >> 7, ii = blk & 127;
  int tid = threadIdx.x;
  int wave = tid >> 6, lane = tid & 63;
  int l15 = lane & 15, quad = lane >> 4;
  int mh = wave & 1;
  int oq = wave >> 1;
  int jloc = mh * 64 + lane;
  int cgrp = oq;

  const int mbase = (bb * 128 + ii) * (NP * 128);

  // ---- window stager: 6 rows x 32 ch x 128 col fp32->fp16, coalesced
  auto stageW = [&](int t, int cg) {
    int wlo = ii + t - 2;
    wlo = wlo < 0 ? 0 : (wlo > 122 ? 122 : wlo);
    const float* xs = x + ((size_t)bb * CIN + cg * 32) * HWSZ;
#pragma unroll
    for (int s = 0; s < 12; ++s) {
      int U = tid + s * 512;
      int colg = U & 31;
      int rc = U >> 5;              // 0..191 = ch*6 + wr
      int ch = rc / 6;
      int wr = rc - ch * 6;
      f32x4 v = *(const f32x4*)(xs + ch * HWSZ + (wlo + wr) * 128 + colg * 4);
      f16x2 p01 = __builtin_amdgcn_cvt_pkrtz(v[0], v[1]);
      f16x2 p23 = __builtin_amdgcn_cvt_pkrtz(v[2], v[3]);
      uint2 wv = make_uint2(__builtin_bit_cast(unsigned, p01),
                            __builtin_bit_cast(unsigned, p23));
      *(uint2*)(smem + ((rc * 128 + colg * 4) << 1)) = wv;
    }
  };

  f32x4 acc[4][4];
#pragma unroll
  for (int mt = 0; mt < 4; ++mt)
#pragma unroll
    for (int ot = 0; ot < 4; ++ot) acc[mt][ot] = (f32x4){0.f, 0.f, 0.f, 0.f};

  // prologue: window (t0,cg0) + meta for chunk 0
  stageW(0, 0);
  int miv = midx[mbase + jloc];
  float4 gv = mw[mbase + jloc];
  __syncthreads();

#pragma unroll 1
  for (int i = 0; i < 36; ++i) {
    int t = i / 12, cg = (i % 12) / 3, nn = i % 3;
    int n = t * 3 + nn;
    (void)nn;

    // ---- B prefetch for this chunk (used after barrier A)
    uint4 bv0, bv1;
    {
      const char* bsrc = (const char*)bt + (n * 128 + cg * 32) * 2;
      int o0 = tid >> 2, gg = tid & 3;
      bv0 = *(const uint4*)(bsrc + (size_t)o0 * 2304 + gg * 16);
      bv1 = *(const uint4*)(bsrc + (size_t)(o0 + 128) * 2304 + gg * 16);
    }
    // ---- meta prefetch for next chunk
    int ip = i + 1;
    int np = (ip < 36) ? ((ip / 12) * 3 + (ip % 3)) : 8;
    int miv_n = midx[mbase + np * 128 + jloc];
    float4 gv_n = mw[mbase + np * 128 + jloc];

    // ---- gather from LDS window (fallback: global, rare)
    int idx = miv; float4 g = gv;
    int r0 = idx & 255, r1 = (idx >> 8) & 255;
    int q0 = (idx >> 16) & 255, q1 = (idx >> 24) & 255;
    int qb = (q0 < 126) ? q0 : 126;
    bool s0 = (q0 != qb), s1 = (q1 != qb);
    int wlo = ii + t - 2;
    wlo = wlo < 0 ? 0 : (wlo > 122 ? 122 : wlo);
    int wr0 = r0 - wlo, wr1 = r1 - wlo;

    bf16x8 av;
    if (__builtin_expect((unsigned)wr0 < 6u && (unsigned)wr1 < 6u, 1)) {
      int e = qb & ~1;
      const unsigned* W32 = (const unsigned*)smem;
      int b0 = (cgrp * 48 + wr0) * 64 + (e >> 1);
      int b1 = (cgrp * 48 + wr1) * 64 + (e >> 1);
      bool odd = (qb & 1);
#pragma unroll
      for (int it = 0; it < 8; ++it) {
        unsigned lo0 = W32[b0 + it * 384], hi0 = W32[b0 + it * 384 + 1];
        unsigned lo1 = W32[b1 + it * 384], hi1 = W32[b1 + it * 384 + 1];
        unsigned sA = odd ? __builtin_amdgcn_alignbit(hi0, lo0, 16) : lo0;
        unsigned sB = odd ? __builtin_amdgcn_alignbit(hi1, lo1, 16) : lo1;
        f16x2 hA = __builtin_bit_cast(f16x2, sA);
        f16x2 hB = __builtin_bit_cast(f16x2, sB);
        float a0 = (float)hA[0], a1 = (float)hA[1];
        float c0f = (float)hB[0], c1f = (float)hB[1];
        float v00 = s0 ? a1 : a0;    // (r0,q0) glt
        float v01 = s1 ? a1 : a0;    // (r0,q1) glb
        float v10 = s0 ? c1f : c0f;  // (r1,q0) grt
        float v11 = s1 ? c1f : c0f;  // (r1,q1) grb
        av[it] = (bf16_t)(g.x * v00 + g.y * v11 + g.z * v01 + g.w * v10);
      }
    } else {
      int oA = r0 * 128 + qb, oB = r1 * 128 + qb;
      const float* p0 = x + ((size_t)bb * CIN + cg * 32 + cgrp * 8) * HWSZ;
#pragma unroll
      for (int it = 0; it < 8; ++it) {
        const float* p = p0 + it * HWSZ;
        F2 pa = *(const F2*)(p + oA);
        F2 pb = *(const F2*)(p + oB);
        float v00 = s0 ? pa.y : pa.x;
        float v01 = s1 ? pa.y : pa.x;
        float v10 = s0 ? pb.y : pb.x;
        float v11 = s1 ? pb.y : pb.x;
        av[it] = (bf16_t)(g.x * v00 + g.y * v11 + g.z * v01 + g.w * v10);
      }
    }

    __syncthreads();   // barrier A: prev frag reads + this window's gather done

    // ---- write A, write B, restage window for next (t,cg) if boundary
    *(bf16x8*)(Ald + jloc * 40 + cgrp * 8) = av;
    {
      int o0 = tid >> 2, gg = tid & 3;
      *(uint4*)((char*)Bld + o0 * 72 + gg * 16) = bv0;
      *(uint4*)((char*)Bld + (o0 + 128) * 72 + gg * 16) = bv1;
    }
    if (ip < 36 && (ip % 3) == 0) stageW(ip / 12, (ip % 12) / 3);

    __syncthreads();   // barrier B

    // ---- fragments + MFMA
    bf16x8 af[4], bfr[4];
#pragma unroll
    for (int mt = 0; mt < 4; ++mt)
      af[mt] = *(bf16x8*)(Ald + (mh * 64 + mt * 16 + l15) * 40 + quad * 8);
#pragma unroll
    for (int ot = 0; ot < 4; ++ot)
      bfr[ot] = *(bf16x8*)(Bld + (oq * 64 + ot * 16 + l15) * 36 + quad * 8);
#pragma unroll
    for (int mt = 0; mt < 4; ++mt)
#pragma unroll
      for (int ot = 0; ot < 4; ++ot)
        acc[mt][ot] = __builtin_amdgcn_mfma_f32_16x16x32_bf16(
            af[mt], bfr[ot], acc[mt][ot], 0, 0, 0);

    miv = miv_n; gv = gv_n;
  }

  // ---- epilogue: transpose 32-o x 128-j pieces through LDS, coalesced stores
  float* piece = (float*)smem;   // 32 x 132 floats (reuses W region)
  for (int p = 0; p < 8; ++p) {
    __syncthreads();
    if (oq == (p >> 1)) {
      int otbase = (p & 1) * 2;
#pragma unroll
      for (int t2 = 0; t2 < 2; ++t2) {
        int ot = otbase + t2;
        int o_ip = t2 * 16 + l15;
#pragma unroll
        for (int mt = 0; mt < 4; ++mt) {
          int jj = mh * 64 + mt * 16 + quad * 4;
          *(f32x4*)(piece + o_ip * 132 + jj) = acc[mt][ot];
        }
      }
    }
    __syncthreads();
#pragma unroll
    for (int s = 0; s < 2; ++s) {
      int id = tid + s * 512;
      int o_ip = id >> 5, part = id & 31;
      f32x4 v = *(f32x4*)(piece + o_ip * 132 + part * 4);
      *(f32x4*)(out + (((size_t)bb * OCH + p * 32 + o_ip) * 128 + ii) * 128 + part * 4) = v;
    }
  }
}

// ---------------------------------------------------------------------------
extern "C" void kernel_launch(void* const* d_in, const int* in_sizes, int n_in,
                              void* d_out, int out_size, void* d_ws, size_t ws_size,
                              hipStream_t stream) {
  const float* x  = (const float*)d_in[0];
  const float* wp = (const float*)d_in[1];
  const float* bp = (const float*)d_in[2];
  const float* wc = (const float*)d_in[3];
  float* out = (float*)d_out;

  bf16_t* BT   = (bf16_t*)d_ws;                              // 589,824 B
  int*    MIDX = (int*)   ((char*)d_ws + (1u << 20));        // 2,359,296 B
  float4* MW   = (float4*)((char*)d_ws + (4u << 20));        // 9,437,184 B

  k_bt<<<dim3(9, 256), 128, 0, stream>>>(wc, BT);
  k_conv_meta<<<512, 512, 0, stream>>>(x, wp, bp, MIDX, MW);
  k_gemm<<<512, 512, 0, stream>>>(x, BT, MIDX, MW, out);
}

// Round 6
// 372.919 us; speedup vs baseline: 1.1415x; 1.1415x over previous
//
#include <hip/hip_runtime.h>
#include <stdint.h>

// Problem constants: B=4, C=128, H=W=128, N=9, OC=256, stride=1
#define CIN   128
#define HDIM  128
#define WDIM  128
#define HWSZ  16384
#define NP    9
#define OCH   256
#define KDIM  1152

typedef __bf16 bf16_t;
typedef __bf16 bf16x8 __attribute__((ext_vector_type(8)));
typedef float  f32x4  __attribute__((ext_vector_type(4)));
struct __attribute__((packed, aligned(4))) F2 { float x, y; };

// Raw workgroup barrier that drains ONLY lgkmcnt (LDS) and leaves vmcnt
// outstanding — __syncthreads() emits s_waitcnt vmcnt(0) which would drain
// our prefetched gather loads every chunk.  0xC07F = vmcnt 63 (no wait),
// expcnt 7 (no wait), lgkmcnt 0 (drain LDS).
__device__ __forceinline__ void bar_lds_only() {
  __builtin_amdgcn_s_waitcnt(0xC07F);
  __builtin_amdgcn_s_barrier();
}

// XCD-locality swizzle (grid=512): XCD k gets a contiguous band of 64
// logical (b,ii) blocks so its 4MB L2 holds the x rows it needs.
__device__ __forceinline__ int swz(int hw) { return (hw & 7) * 64 + (hw >> 3); }

// ---------------------------------------------------------------------------
// B_T[o][k] bf16, k = n*128 + c  (= w_conv[o][c][n])
// ---------------------------------------------------------------------------
__global__ void k_bt(const float* __restrict__ wc, bf16_t* __restrict__ bt) {
  int c = threadIdx.x, n = blockIdx.x, o = blockIdx.y;
  bt[o * KDIM + n * 128 + c] = (bf16_t)wc[(o * CIN + c) * NP + n];
}

// ---------------------------------------------------------------------------
// WR[c][o*9+t] = wp[o][c][t]: per-channel-contiguous 162 floats so the conv's
// uniform weight reads merge into wide s_load_dwordx4/x8.
// ---------------------------------------------------------------------------
__global__ void k_wr(const float* __restrict__ wp, float* __restrict__ wr) {
  int c = blockIdx.x, idx = threadIdx.x;     // 128 blocks x 192 thr
  if (idx < 162) {
    int o = idx / 9, t = idx - o * 9;
    wr[c * 162 + idx] = wp[o * 1152 + c * 9 + t];
  }
}

// ---------------------------------------------------------------------------
// Offset conv (3x3 pad 1, 128->18) in PURE FP32 + bilinear meta.
// fp32 REQUIRED: bilinear is discontinuous at borders (clamped corner weights
// sum to 2); ~1e-3 offset error flips samples (round-2 failure).
// 512 threads = 128 j x 4 c-quarters. Weights from WR (contiguous per c).
// ---------------------------------------------------------------------------
__global__ __launch_bounds__(512) void k_conv_meta(
    const float* __restrict__ x, const float* __restrict__ wrp,
    const float* __restrict__ bp, int* __restrict__ midx,
    float4* __restrict__ mw)
{
  __shared__ float red[4 * 128 * 19];   // [cq][j] stride 19: conflict-free

  int blk = swz(blockIdx.x);
  int bb = blk >> 7, ii = blk & 127;
  int tid = threadIdx.x;
  int j = tid & 127;
  int cq = tid >> 7;          // wave-uniform

  float acc[18];
#pragma unroll
  for (int o = 0; o < 18; ++o) acc[o] = 0.f;

  for (int c = cq * 32; c < cq * 32 + 32; ++c) {
    int cu = __builtin_amdgcn_readfirstlane(c);
    const float* xc = x + ((size_t)bb * CIN + cu) * HWSZ;
    float xv[9];
#pragma unroll
    for (int dy = 0; dy < 3; ++dy) {
      int r = ii + dy - 1;
      bool rok = ((unsigned)r < 128u);
#pragma unroll
      for (int dx = 0; dx < 3; ++dx) {
        int cc = j + dx - 1;
        bool ok = rok && ((unsigned)cc < 128u);
        xv[dy * 3 + dx] = ok ? xc[r * 128 + cc] : 0.f;   // j-coalesced
      }
    }
    const float* wr = wrp + cu * 162;   // uniform, contiguous -> wide s_load
#pragma unroll
    for (int o = 0; o < 18; ++o) {
#pragma unroll
      for (int t = 0; t < 9; ++t)
        acc[o] += xv[t] * wr[o * 9 + t];
    }
  }

  {
    float* rr = &red[(cq * 128 + j) * 19];
#pragma unroll
    for (int o = 0; o < 18; ++o) rr[o] = acc[o];
  }
  __syncthreads();

  if (tid < 128) {
#pragma unroll
    for (int o = 0; o < 18; ++o)
      acc[o] = red[(0 * 128 + j) * 19 + o] + red[(1 * 128 + j) * 19 + o] +
               red[(2 * 128 + j) * 19 + o] + red[(3 * 128 + j) * 19 + o];

#pragma unroll
    for (int n = 0; n < NP; ++n) {
      float offx = acc[n] + bp[n];
      float offy = acc[9 + n] + bp[9 + n];
      float px = (float)ii + (float)(n / 3) + offx;
      float py = (float)j  + (float)(n % 3) + offy;
      float f0 = floorf(px), f1 = f0 + 1.f;
      float h0 = floorf(py), h1 = h0 + 1.f;
      int r0 = (int)fminf(fmaxf(f0, 0.f), 127.f);
      int r1 = (int)fminf(fmaxf(f1, 0.f), 127.f);
      int c0 = (int)fminf(fmaxf(h0, 0.f), 127.f);
      int c1 = (int)fminf(fmaxf(h1, 0.f), 127.f);
      float pxc = fminf(fmaxf(px, 0.f), 127.f);
      float pyc = fminf(fmaxf(py, 0.f), 127.f);
      float glt = (1.f + ((float)r0 - pxc)) * (1.f + ((float)c0 - pyc));
      float grb = (1.f - ((float)r1 - pxc)) * (1.f - ((float)c1 - pyc));
      float glb = (1.f + ((float)r0 - pxc)) * (1.f - ((float)c1 - pyc));
      float grt = (1.f - ((float)r1 - pxc)) * (1.f + ((float)c0 - pyc));
      int base = ((bb * 128 + ii) * NP + n) * 128 + j;
      midx[base] = r0 | (r1 << 8) | (c0 << 16) | (c1 << 24);
      mw[base] = make_float4(glt, grb, glb, grt);
    }
  }
}

// ---------------------------------------------------------------------------
// Fused gather + GEMM, software-pipelined. One block per (b,ii):
// Mtile=128 (j), Ntile=256 (o). 512 threads = 8 waves; wave (mh,oq) owns
// 64m x 64o. Chunk kk: n=kk>>2, c-group=(kk&3)*32 (round-3 order/math).
// Pipeline: scattered gather loads + B loads for chunk kk+1 issue after
// chunk kk's LDS writes; raw lgkm-only barriers keep them in flight through
// the MFMAs — removes L2 latency from the per-chunk critical path (round 3
// was latency-serialized at 174us with all pipes <20% busy).
// LDS: A 128x40 bf16 (80B rows) | B 256x36 bf16 (72B rows, conflict-free).
// ---------------------------------------------------------------------------
__global__ __launch_bounds__(512) void k_gemm(
    const float* __restrict__ x, const bf16_t* __restrict__ bt,
    const int* __restrict__ midx, const float4* __restrict__ mw,
    float* __restrict__ out)
{
  __shared__ __align__(16) char smem[28672];
  bf16_t* Ald = (bf16_t*)smem;              // 10240 B
  bf16_t* Bld = (bf16_t*)(smem + 10240);    // 18432 B

  int blk = swz(blockIdx.x);
  int bb = blk >> 7, ii = blk & 127;
  int tid = threadIdx.x;
  int wave = tid >> 6, lane = tid & 63;
  int l15 = lane & 15, quad = lane >> 4;
  int mh = wave & 1;
  int oq = wave >> 1;
  int jloc = mh * 64 + lane;
  int cgrp = oq;

  const int mbase = (bb * 128 + ii) * (NP * 128) + jloc;
  const float* xb = x + (size_t)bb * CIN * HWSZ + (size_t)cgrp * 8 * HWSZ;
  const int o0 = tid >> 2, gg = tid & 3;
  const char* bsrc = (const char*)bt + gg * 16;

  // pipeline registers
  F2 cA[8], cB[8];          // gathered corners, rows r0/r1, 8 channels
  uint4 bv0, bv1;           // B stage data
  int miv_c, miv_n;         // meta (packed indices) for current / next n
  float4 gv_c, gv_n;

  f32x4 acc[4][4];
#pragma unroll
  for (int mt = 0; mt < 4; ++mt)
#pragma unroll
    for (int ot = 0; ot < 4; ++ot) acc[mt][ot] = (f32x4){0.f, 0.f, 0.f, 0.f};

  // issue gather for chunk kk using meta mi
  auto issueG = [&](int kk, int mi) {
    int r0 = mi & 255, r1 = (mi >> 8) & 255;
    int q0 = (mi >> 16) & 255;
    int qb = (q0 < 126) ? q0 : 126;
    int oA = r0 * 128 + qb, oB = r1 * 128 + qb;
    const float* p0 = xb + (size_t)(kk & 3) * 32 * HWSZ;
#pragma unroll
    for (int it = 0; it < 8; ++it) {
      cA[it] = *(const F2*)(p0 + it * HWSZ + oA);
      cB[it] = *(const F2*)(p0 + it * HWSZ + oB);
    }
  };
  auto issueB = [&](int kk) {
    const char* bp_ = bsrc + kk * 64;
    bv0 = *(const uint4*)(bp_ + (size_t)o0 * 2304);
    bv1 = *(const uint4*)(bp_ + (size_t)(o0 + 128) * 2304);
  };

  // ---- prologue: meta(n=0), gather(0), B(0)
  miv_c = midx[mbase];
  gv_c  = mw[mbase];
  issueG(0, miv_c);
  issueB(0);

#pragma unroll 1
  for (int i = 0; i < 36; ++i) {
    // ---- combine chunk i's corners (vmcnt wait inserted by compiler)
    int mi = miv_c; float4 g = gv_c;
    int q0 = (mi >> 16) & 255, q1 = (mi >> 24) & 255;
    int qb = (q0 < 126) ? q0 : 126;
    float s0 = (q0 != qb) ? 1.f : 0.f, s1 = (q1 != qb) ? 1.f : 0.f;
    float wA0 = g.x * (1.f - s0) + g.z * (1.f - s1);  // row r0, col qb
    float wA1 = g.x * s0 + g.z * s1;                  // row r0, col qb+1
    float wB0 = g.w * (1.f - s0) + g.y * (1.f - s1);  // row r1, col qb
    float wB1 = g.w * s0 + g.y * s1;                  // row r1, col qb+1
    bf16x8 av;
#pragma unroll
    for (int it = 0; it < 8; ++it)
      av[it] = (bf16_t)(wA0 * cA[it].x + wA1 * cA[it].y +
                        wB0 * cB[it].x + wB1 * cB[it].y);

    bar_lds_only();   // frag reads of chunk i-1 complete

    // ---- LDS stores for chunk i
    *(bf16x8*)(Ald + jloc * 40 + cgrp * 8) = av;
    *(uint4*)((char*)Bld + o0 * 72 + gg * 16) = bv0;
    *(uint4*)((char*)Bld + (o0 + 128) * 72 + gg * 16) = bv1;

    // ---- issue loads for chunk i+1 (stay in flight through the MFMAs)
    if ((i & 3) == 0 && (i >> 2) + 1 < 9) {       // prefetch meta for n+1
      int nb = mbase + ((i >> 2) + 1) * 128;
      miv_n = midx[nb];
      gv_n  = mw[nb];
    }
    if (i < 35) {
      int mi2 = (((i + 1) & 3) == 0) ? miv_n : miv_c;
      issueG(i + 1, mi2);
      issueB(i + 1);
    }

    bar_lds_only();   // A/B writes visible

    // ---- fragments + MFMA for chunk i
    bf16x8 af[4], bfr[4];
#pragma unroll
    for (int mt = 0; mt < 4; ++mt)
      af[mt] = *(bf16x8*)(Ald + (mh * 64 + mt * 16 + l15) * 40 + quad * 8);
#pragma unroll
    for (int ot = 0; ot < 4; ++ot)
      bfr[ot] = *(bf16x8*)(Bld + (oq * 64 + ot * 16 + l15) * 36 + quad * 8);
#pragma unroll
    for (int mt = 0; mt < 4; ++mt)
#pragma unroll
      for (int ot = 0; ot < 4; ++ot)
        acc[mt][ot] = __builtin_amdgcn_mfma_f32_16x16x32_bf16(
            af[mt], bfr[ot], acc[mt][ot], 0, 0, 0);

    if (((i + 1) & 3) == 0) { miv_c = miv_n; gv_c = gv_n; }  // rotate meta
  }

  // ---- epilogue: transpose 32-o x 128-j pieces through LDS, coalesced stores
  float* piece = (float*)smem;   // 32 x 132 floats (needs 16896 B < 28672)
  for (int p = 0; p < 8; ++p) {
    __syncthreads();
    if (oq == (p >> 1)) {
      int otbase = (p & 1) * 2;
#pragma unroll
      for (int t2 = 0; t2 < 2; ++t2) {
        int ot = otbase + t2;
        int o_ip = t2 * 16 + l15;
#pragma unroll
        for (int mt = 0; mt < 4; ++mt) {
          int jj = mh * 64 + mt * 16 + quad * 4;
          *(f32x4*)(piece + o_ip * 132 + jj) = acc[mt][ot];
        }
      }
    }
    __syncthreads();
#pragma unroll
    for (int s = 0; s < 2; ++s) {
      int id = tid + s * 512;
      int o_ip = id >> 5, part = id & 31;
      f32x4 v = *(f32x4*)(piece + o_ip * 132 + part * 4);
      *(f32x4*)(out + (((size_t)bb * OCH + p * 32 + o_ip) * 128 + ii) * 128 + part * 4) = v;
    }
  }
}

// ---------------------------------------------------------------------------
extern "C" void kernel_launch(void* const* d_in, const int* in_sizes, int n_in,
                              void* d_out, int out_size, void* d_ws, size_t ws_size,
                              hipStream_t stream) {
  const float* x  = (const float*)d_in[0];
  const float* wp = (const float*)d_in[1];
  const float* bp = (const float*)d_in[2];
  const float* wc = (const float*)d_in[3];
  float* out = (float*)d_out;

  bf16_t* BT   = (bf16_t*)d_ws;                              // 589,824 B
  float*  WR   = (float*) ((char*)d_ws + 655360);            // 82,944 B
  int*    MIDX = (int*)   ((char*)d_ws + (1u << 20));        // 2,359,296 B
  float4* MW   = (float4*)((char*)d_ws + (4u << 20));        // 9,437,184 B

  k_bt<<<dim3(9, 256), 128, 0, stream>>>(wc, BT);
  k_wr<<<128, 192, 0, stream>>>(wp, WR);
  k_conv_meta<<<512, 512, 0, stream>>>(x, WR, bp, MIDX, MW);
  k_gemm<<<512, 512, 0, stream>>>(x, BT, MIDX, MW, out);
}